// Round 8
// baseline (251.579 us; speedup 1.0000x reference)
//
#include <hip/hip_runtime.h>
#include <math.h>

// Problem constants
#define C_DIM 512
#define NHEAD 8
#define HDIM 64
#define NTOK 8000
#define BN_TOK 16000
#define MPAD 16384   // BN_TOK padded to 128 row-tiles for the XCD swizzle

typedef __attribute__((ext_vector_type(8))) short bf16x8;
typedef __attribute__((ext_vector_type(4))) float f32x4;
typedef __attribute__((ext_vector_type(2))) _Float16 h2;
typedef unsigned short u16;

__device__ __forceinline__ int imin(int a, int b) { return a < b ? a : b; }

// fp32 -> bf16 round-to-nearest-even
__device__ __forceinline__ u16 f2bf(float x) {
    union { float f; unsigned u; } c; c.f = x;
    unsigned r = c.u + 0x7FFFu + ((c.u >> 16) & 1u);
    return (u16)(r >> 16);
}

// fp32 -> f16 (RNE)
__device__ __forceinline__ u16 f2h(float x) {
    _Float16 h = (_Float16)x;
    return __builtin_bit_cast(u16, h);
}

// async global->LDS, 16 bytes per lane (global_load_lds_dwordx4)
__device__ __forceinline__ void async16(const void* g, void* l) {
    __builtin_amdgcn_global_load_lds(
        (const __attribute__((address_space(1))) void*)g,
        (__attribute__((address_space(3))) void*)l, 16, 0, 0);
}

// fma of 8 f16 channels (one uint4) into fp32 acc — v_fma_mix_f32 path
__device__ __forceinline__ void fmah(float* a, const uint4& d, float w) {
    h2 v0 = __builtin_bit_cast(h2, d.x);
    h2 v1 = __builtin_bit_cast(h2, d.y);
    h2 v2 = __builtin_bit_cast(h2, d.z);
    h2 v3 = __builtin_bit_cast(h2, d.w);
    a[0] = fmaf((float)v0.x, w, a[0]);
    a[1] = fmaf((float)v0.y, w, a[1]);
    a[2] = fmaf((float)v1.x, w, a[2]);
    a[3] = fmaf((float)v1.y, w, a[3]);
    a[4] = fmaf((float)v2.x, w, a[4]);
    a[5] = fmaf((float)v2.y, w, a[5]);
    a[6] = fmaf((float)v3.x, w, a[6]);
    a[7] = fmaf((float)v3.y, w, a[7]);
}

// ---------------------------------------------------------------------------
// f_kv (B,C,N) fp32 -> kvT (B,N,C) f16. Fixed 512 x 8000 per batch.
// ---------------------------------------------------------------------------
__global__ __launch_bounds__(256) void transpose_c2l_f16(
    const float* __restrict__ in, u16* __restrict__ out)
{
    __shared__ float tile[32][33];
    int b = blockIdx.z;
    const float* inb = in + (size_t)b * 512 * NTOK;
    u16* outb = out + (size_t)b * NTOK * 512;
    int s0 = blockIdx.x * 32, r0 = blockIdx.y * 32;   // s: token, r: channel
    int tx = threadIdx.x & 31, ty = threadIdx.x >> 5;
#pragma unroll
    for (int i = 0; i < 4; i++)
        tile[ty + i * 8][tx] = inb[(size_t)(r0 + ty + i * 8) * NTOK + s0 + tx];
    __syncthreads();
    int rq = threadIdx.x & 7, sy = threadIdx.x >> 3;  // rq: channel quad, sy: token
    ushort4 o;
    o.x = f2h(tile[rq * 4 + 0][sy]);
    o.y = f2h(tile[rq * 4 + 1][sy]);
    o.z = f2h(tile[rq * 4 + 2][sy]);
    o.w = f2h(tile[rq * 4 + 3][sy]);
    *reinterpret_cast<ushort4*>(outb + (size_t)(s0 + sy) * 512 + r0 + rq * 4) = o;
}

// ---------------------------------------------------------------------------
// Merged weight converts: z selects which W (512 x Nout) fp32 -> (Npad x 512)
// bf16, pad rows zeroed. Grid (16,16,5); small weights early-out on x.
// ---------------------------------------------------------------------------
__global__ __launch_bounds__(256) void wcvt_all(
    const float* __restrict__ W0, u16* __restrict__ T0,
    const float* __restrict__ W1, u16* __restrict__ T1,
    const float* __restrict__ W2, u16* __restrict__ T2,
    const float* __restrict__ W3, u16* __restrict__ T3,
    const float* __restrict__ W4, u16* __restrict__ T4)
{
    const float* W; u16* Wt; int Nout, Npad;
    switch (blockIdx.z) {
        case 0: W = W0; Wt = T0; Nout = 512; Npad = 512; break;
        case 1: W = W1; Wt = T1; Nout = 512; Npad = 512; break;
        case 2: W = W2; Wt = T2; Nout = 512; Npad = 512; break;
        case 3: W = W3; Wt = T3; Nout = 96;  Npad = 128; break;
        default: W = W4; Wt = T4; Nout = 32; Npad = 128; break;
    }
    int n0 = blockIdx.x * 32, k0 = blockIdx.y * 32;
    if (n0 >= Npad) return;
    __shared__ float t[32][33];
    int tx = threadIdx.x & 31, ty = threadIdx.x >> 5;
#pragma unroll
    for (int i = 0; i < 4; i++) {
        int k = k0 + ty + i * 8, n = n0 + tx;
        t[ty + i * 8][tx] = (n < Nout) ? W[(size_t)k * Nout + n] : 0.f;
    }
    __syncthreads();
#pragma unroll
    for (int i = 0; i < 4; i++) {
        int n = n0 + ty + i * 8, k = k0 + tx;
        Wt[(size_t)n * 512 + k] = f2bf(t[tx][ty + i * 8]);
    }
}

// ---------------------------------------------------------------------------
// Fused LayerNorm + (B,C,N)->(B,N,C) transpose, LDS-tiled for ideal fetch.
// ---------------------------------------------------------------------------
__global__ __launch_bounds__(256) void ln_fused(
    const float* __restrict__ fq, const float* __restrict__ gamma,
    const float* __restrict__ beta, u16* __restrict__ q)
{
    __shared__ float tile[512][33];   // [c][t], 67.6 KB
    __shared__ float ps[32][17], pq[32][17];
    __shared__ float muA[32], rsA[32];
    int blk = blockIdx.x;
    int b = blk / 250;
    int n0 = (blk - b * 250) * 32;
    const float* src = fq + (size_t)b * C_DIM * NTOK + n0;
    int tid = threadIdx.x;
    int cgrp = tid >> 4;          // 0..15
    int tp = (tid & 15) * 2;      // 0,2,..,30
    float s0 = 0.f, q0 = 0.f, s1 = 0.f, q1 = 0.f;
#pragma unroll 4
    for (int it = 0; it < 32; ++it) {
        int c = it * 16 + cgrp;
        float2 v = *reinterpret_cast<const float2*>(src + (size_t)c * NTOK + tp);
        tile[c][tp] = v.x; tile[c][tp + 1] = v.y;
        s0 += v.x; q0 += v.x * v.x;
        s1 += v.y; q1 += v.y * v.y;
    }
    ps[tp][cgrp] = s0; pq[tp][cgrp] = q0;
    ps[tp + 1][cgrp] = s1; pq[tp + 1][cgrp] = q1;
    int lane = tid & 63, wv = tid >> 6;
    float4 g0 = *reinterpret_cast<const float4*>(gamma + lane * 4);
    float4 be0 = *reinterpret_cast<const float4*>(beta + lane * 4);
    float4 g1 = *reinterpret_cast<const float4*>(gamma + 256 + lane * 4);
    float4 be1 = *reinterpret_cast<const float4*>(beta + 256 + lane * 4);
    __syncthreads();
    if (tid < 32) {
        float S = 0.f, SQ = 0.f;
#pragma unroll
        for (int g = 0; g < 16; ++g) { S += ps[tid][g]; SQ += pq[tid][g]; }
        float mu = S * (1.f / 512.f);
        float var = SQ * (1.f / 512.f) - mu * mu;
        muA[tid] = mu;
        rsA[tid] = rsqrtf(var + 1e-5f);
    }
    __syncthreads();
#pragma unroll
    for (int it = 0; it < 16; ++it) {
        int task = it * 4 + wv;     // 0..63 : (token, half)
        int t = task >> 1, h = task & 1;
        int c0 = h * 256 + lane * 4;
        float mu = muA[t], rs = rsA[t];
        float4 g = h ? g1 : g0, bb = h ? be1 : be0;
        ushort4 o;
        o.x = f2bf((tile[c0 + 0][t] - mu) * rs * g.x + bb.x);
        o.y = f2bf((tile[c0 + 1][t] - mu) * rs * g.y + bb.y);
        o.z = f2bf((tile[c0 + 2][t] - mu) * rs * g.z + bb.z);
        o.w = f2bf((tile[c0 + 3][t] - mu) * rs * g.w + bb.w);
        *reinterpret_cast<ushort4*>(q + ((size_t)(b * NTOK + n0 + t)) * C_DIM + c0) = o;
    }
}

// ---------------------------------------------------------------------------
// bf16 MFMA GEMM body, BK=64: C[M,Nout] = A[M,512] @ Bt[.,512]^T.
// 128x128 tile, 8 K-iterations, 32 KB LDS, XOR swizzle (2-way = free, m136).
// mode 0: fp32 row-major (ldc), bias[col], rows guarded by Mrows
// mode 1: bf16 row-major (ldc), bias[col], rows guarded by Mrows
// mode 2: fp32 direct (B,C,N) store — rows=channels, cols=tokens; bias[row].
// ---------------------------------------------------------------------------
__device__ __forceinline__ void gemm_body(
    const u16* __restrict__ A, const u16* __restrict__ Bt,
    const float* __restrict__ bias, float* __restrict__ Cf,
    u16* __restrict__ Cb, int Nout, int ldc, int relu, int mode, int Mrows,
    int bx, int by)
{
    __shared__ u16 As[128 * 64];  // 16 KB
    __shared__ u16 Bs[128 * 64];
    int tid = threadIdx.x, lane = tid & 63, wv = tid >> 6;
    int bm = by * 128, bn = bx * 128;
    int wm = (wv >> 1) * 64, wn = (wv & 1) * 64;

    f32x4 acc[4][4];
#pragma unroll
    for (int i = 0; i < 4; i++)
#pragma unroll
        for (int j = 0; j < 4; j++) acc[i][j] = (f32x4){0.f, 0.f, 0.f, 0.f};

    int rS[4], sS[4], dS[4];
#pragma unroll
    for (int c = 0; c < 4; c++) {
        int lin = (c * 4 + wv) * 64 + lane;
        rS[c] = lin >> 3;
        sS[c] = (lin & 7) ^ (rS[c] & 7);
        dS[c] = lin * 8;   // u16 units
    }

    const u16* Ab = A + (size_t)bm * 512;
    const u16* Bb = Bt + (size_t)bn * 512;

    int ml = lane & 15, quad = lane >> 4;
    int offA[4][2], offB[4][2];
#pragma unroll
    for (int i = 0; i < 4; i++) {
        int r = wm + i * 16 + ml;
        int rb = wn + i * 16 + ml;
#pragma unroll
        for (int kk = 0; kk < 2; kk++) {
            offA[i][kk] = r * 64 + (((kk * 4 + quad) ^ (r & 7)) * 8);
            offB[i][kk] = rb * 64 + (((kk * 4 + quad) ^ (rb & 7)) * 8);
        }
    }

    for (int k0 = 0; k0 < 512; k0 += 64) {
#pragma unroll
        for (int c = 0; c < 4; c++) {
            async16(Ab + (size_t)rS[c] * 512 + k0 + sS[c] * 8, As + dS[c]);
            async16(Bb + (size_t)rS[c] * 512 + k0 + sS[c] * 8, Bs + dS[c]);
        }
        __syncthreads();
#pragma unroll
        for (int kk = 0; kk < 2; kk++) {
            bf16x8 af[4], bfr[4];
#pragma unroll
            for (int i = 0; i < 4; i++) {
                af[i]  = *reinterpret_cast<const bf16x8*>(As + offA[i][kk]);
                bfr[i] = *reinterpret_cast<const bf16x8*>(Bs + offB[i][kk]);
            }
#pragma unroll
            for (int i = 0; i < 4; i++)
#pragma unroll
                for (int j = 0; j < 4; j++)
                    acc[i][j] = __builtin_amdgcn_mfma_f32_16x16x32_bf16(
                        af[i], bfr[j], acc[i][j], 0, 0, 0);
        }
        __syncthreads();
    }

    // epilogue: C/D layout col=lane&15, row=quad*4+reg (m89/m91 verified)
#pragma unroll
    for (int i = 0; i < 4; i++) {
        int row = bm + wm + i * 16 + quad * 4;
#pragma unroll
        for (int j = 0; j < 4; j++) {
            int col = bn + wn + j * 16 + ml;
            if (col < Nout) {
                float bia = (mode == 2) ? 0.f : bias[col];
#pragma unroll
                for (int rg = 0; rg < 4; rg++) {
                    if (row + rg >= Mrows) continue;
                    float v = acc[i][j][rg] + ((mode == 2) ? bias[row + rg] : bia);
                    if (relu) v = fmaxf(v, 0.f);
                    if (mode == 2) {
                        int bb = col >= 8000;
                        int nn = col - bb * 8000;
                        Cf[((size_t)(bb * 512 + row + rg)) * 8000 + nn] = v;
                    } else {
                        size_t idx = (size_t)(row + rg) * ldc + col;
                        if (mode == 1) Cb[idx] = f2bf(v);
                        else           Cf[idx] = v;
                    }
                }
            }
        }
    }
}

// XCD-swizzled big GEMM: 1D grid of 512 blocks. x = L&7 (assumed XCD via
// round-robin), t = L>>3. mode 0/1: the 4 col-tiles sharing a row-tile get
// consecutive L on the SAME XCD -> A row-block (2 MB/XCD) is L2-resident
// instead of re-fetched by 4 XCDs. mode 2: symmetric for B (token) tiles.
__global__ __launch_bounds__(256) void gemm_swz(
    const u16* __restrict__ A, const u16* __restrict__ Bt,
    const float* __restrict__ bias, float* __restrict__ Cf,
    u16* __restrict__ Cb, int Nout, int ldc, int relu, int mode, int Mrows)
{
    int L = blockIdx.x;
    int x = L & 7, t = L >> 3;
    int bx, by;
    if (mode == 2) { by = t & 3; bx = x * 16 + (t >> 2); }
    else           { bx = t & 3; by = x * 16 + (t >> 2); }
    gemm_body(A, Bt, bias, Cf, Cb, Nout, ldc, relu, mode, Mrows, bx, by);
}

// Two independent small GEMMs in one dispatch (z selects operand set).
__global__ __launch_bounds__(256) void gemm_dual(
    const u16* __restrict__ A0, const u16* __restrict__ B0,
    const float* __restrict__ bias0, float* __restrict__ C0, int N0,
    const u16* __restrict__ A1, const u16* __restrict__ B1,
    const float* __restrict__ bias1, float* __restrict__ C1, int N1)
{
    if (blockIdx.z == 0)
        gemm_body(A0, B0, bias0, C0, nullptr, N0, N0, 0, 0, BN_TOK,
                  blockIdx.x, blockIdx.y);
    else
        gemm_body(A1, B1, bias1, C1, nullptr, N1, N1, 0, 0, BN_TOK,
                  blockIdx.x, blockIdx.y);
}

// ---------------------------------------------------------------------------
// Fused softmax + offset clip + trilinear sample + einsum, f16 volume.
// One wave = one token (8 heads); lane = h*8 + cl, 8 channels/lane via one
// uint4 (8 x f16) corner load, f16->f32 via v_fma_mix. attn folded into
// corner weights. p-loop NOT unrolled: full unroll hit 132 VGPR -> 9% occ
// (R6). 32-bit element offsets avoid v_mad_u64 chains.
// XCD swizzle: blockIdx.x & 7 -> 2000-token contiguous slab per XCD.
// Reference quirk: off-ch0 -> W(x) axis, ch1 -> H(y), ch2 -> D(z); H=W=D=20
// collapses normalization to clip(base+off, 0, 19).
// ---------------------------------------------------------------------------
__global__ __launch_bounds__(256) void sample_kernel(
    const u16* __restrict__ vol, const float* __restrict__ offb,
    const float* __restrict__ lgb, u16* __restrict__ outp)
{
    int wid = threadIdx.x >> 6, lane = threadIdx.x & 63;
    int bx = blockIdx.x;                               // 4000 = 8 slabs x 500
    int bn = ((bx & 7) * 500 + (bx >> 3)) * 4 + wid;   // token 0..15999
    int h = lane >> 3, cl = lane & 7;
    int b = bn / NTOK, n = bn - b * NTOK;
    int y = n / 400;
    int r2 = n - y * 400;
    int x = r2 / 20;
    int z = r2 - x * 20;

    const float* op = offb + (size_t)bn * 96 + h * 12;
    const float* lp = lgb + (size_t)bn * 32 + h * 4;
    float l0 = lp[0], l1 = lp[1], l2 = lp[2], l3 = lp[3];
    float mx = fmaxf(fmaxf(l0, l1), fmaxf(l2, l3));
    float e0 = expf(l0 - mx), e1 = expf(l1 - mx), e2 = expf(l2 - mx), e3 = expf(l3 - mx);
    float inv = 1.f / (e0 + e1 + e2 + e3);
    float at[4] = {e0 * inv, e1 * inv, e2 * inv, e3 * inv};

    const u16* volb = vol + b * (NTOK * C_DIM) + h * HDIM + cl * 8;
    float acc[8] = {};
#pragma unroll 1
    for (int p = 0; p < 4; p++) {
        float o0 = fminf(fmaxf(op[p * 3 + 0], -3.f), 3.f);
        float o1 = fminf(fmaxf(op[p * 3 + 1], -3.f), 3.f);
        float o2 = fminf(fmaxf(op[p * 3 + 2], -3.f), 3.f);
        float ix = fminf(fmaxf((float)y + o0, 0.f), 19.f);  // W axis
        float iy = fminf(fmaxf((float)x + o1, 0.f), 19.f);  // H axis
        float iz = fminf(fmaxf((float)z + o2, 0.f), 19.f);  // D axis
        float xf = floorf(ix), yf = floorf(iy), zf = floorf(iz);
        float fx = ix - xf, fy = iy - yf, fz = iz - zf;
        int x0 = (int)xf, y0 = (int)yf, z0 = (int)zf;
        int x1 = imin(x0 + 1, 19), y1 = imin(y0 + 1, 19), z1 = imin(z0 + 1, 19);
        // spatial = yi*400 + xi*20 + zi, channels contiguous (stride C_DIM)
        int s00 = y0 * 400 + x0 * 20, s01 = y0 * 400 + x1 * 20;
        int s10 = y1 * 400 + x0 * 20, s11 = y1 * 400 + x1 * 20;
        uint4 v000 = *(const uint4*)(volb + (s00 + z0) * C_DIM);
        uint4 v001 = *(const uint4*)(volb + (s01 + z0) * C_DIM);
        uint4 v010 = *(const uint4*)(volb + (s10 + z0) * C_DIM);
        uint4 v011 = *(const uint4*)(volb + (s11 + z0) * C_DIM);
        uint4 v100 = *(const uint4*)(volb + (s00 + z1) * C_DIM);
        uint4 v101 = *(const uint4*)(volb + (s01 + z1) * C_DIM);
        uint4 v110 = *(const uint4*)(volb + (s10 + z1) * C_DIM);
        uint4 v111 = *(const uint4*)(volb + (s11 + z1) * C_DIM);
        float wz0 = (1.f - fz) * at[p], wz1 = fz * at[p];
        float w00 = wz0 * (1.f - fy), w01 = wz0 * fy;
        float w10 = wz1 * (1.f - fy), w11 = wz1 * fy;
        float gx0 = 1.f - fx;
        fmah(acc, v000, w00 * gx0); fmah(acc, v001, w00 * fx);
        fmah(acc, v010, w01 * gx0); fmah(acc, v011, w01 * fx);
        fmah(acc, v100, w10 * gx0); fmah(acc, v101, w10 * fx);
        fmah(acc, v110, w11 * gx0); fmah(acc, v111, w11 * fx);
    }
    u16 ov[8];
#pragma unroll
    for (int c = 0; c < 8; c++) ov[c] = f2bf(acc[c]);
    *reinterpret_cast<uint4*>(outp + (size_t)bn * C_DIM + h * HDIM + cl * 8) =
        *reinterpret_cast<uint4*>(ov);
}

// ---------------------------------------------------------------------------
// Launch
// ---------------------------------------------------------------------------
extern "C" void kernel_launch(void* const* d_in, const int* in_sizes, int n_in,
                              void* d_out, int out_size, void* d_ws, size_t ws_size,
                              hipStream_t stream)
{
    const float* f_query = (const float*)d_in[0];
    const float* f_kv    = (const float*)d_in[1];
    const float* ln_g    = (const float*)d_in[2];
    const float* ln_b    = (const float*)d_in[3];
    const float* Wq      = (const float*)d_in[4];
    const float* bq      = (const float*)d_in[5];
    const float* Wo1     = (const float*)d_in[6];
    const float* bo1     = (const float*)d_in[7];
    const float* Wo2     = (const float*)d_in[8];
    const float* bo2     = (const float*)d_in[9];
    const float* Wa      = (const float*)d_in[10];
    const float* ba      = (const float*)d_in[11];
    const float* Wout    = (const float*)d_in[12];
    const float* bout    = (const float*)d_in[13];
    float* out = (float*)d_out;

    float* ws = (float*)d_ws;
    float* offb = ws;                        // 1,536,000 f
    float* lgb  = ws + 1536000;              //   512,000 f
    u16* base  = (u16*)(ws + 2048000);
    u16* kvT   = base;                       // 16000 x 512 (f16 channels-last)
    u16* qb    = base +  8192000;            // MPAD x 512 (q; later sampled)
    u16* Qb    = qb   +  (size_t)MPAD * 512; // MPAD x 512
    u16* hid   = Qb   +  (size_t)MPAD * 512; // MPAD x 512
    u16* WqT   = hid  +  (size_t)MPAD * 512;
    u16* Wo1T  = WqT + 262144;
    u16* WoutT = Wo1T + 262144;
    u16* Wo2T  = WoutT + 262144;             // 128x512 (96 valid, pad 0)
    u16* WaT   = Wo2T + 65536;               // 128x512 (32 valid, pad 0)
    // total ~77 MiB

    dim3 blk(256);
    // all weight transpose-converts in one dispatch
    wcvt_all<<<dim3(16, 16, 5), blk, 0, stream>>>(
        Wq, WqT, Wo1, Wo1T, Wout, WoutT, Wo2, Wo2T, Wa, WaT);
    // f_kv (B,C,N) fp32 -> kvT (B,N,C) f16
    transpose_c2l_f16<<<dim3(250, 16, 2), blk, 0, stream>>>(f_kv, kvT);
    // q = LN(transpose(f_query)) -> bf16, fused LDS tile
    ln_fused<<<dim3(500), blk, 0, stream>>>(f_query, ln_g, ln_b, qb);
    // Q = q @ Wq + bq -> bf16 (XCD-swizzled, M padded to 16384)
    gemm_swz<<<dim3(512), blk, 0, stream>>>(qb, WqT, bq, nullptr, Qb,
                                            512, 512, 0, 1, BN_TOK);
    // hidden = relu(Q @ Wo1 + bo1) -> bf16
    gemm_swz<<<dim3(512), blk, 0, stream>>>(Qb, Wo1T, bo1, nullptr, hid,
                                            512, 512, 1, 1, BN_TOK);
    // off = hidden @ Wo2 + bo2 (fp32) AND logits = Q @ Wa + ba (fp32)
    gemm_dual<<<dim3(1, 125, 2), blk, 0, stream>>>(
        hid, Wo2T, bo2, offb, 96, Qb, WaT, ba, lgb, 32);
    // fused sample/softmax/einsum -> qb (bf16)
    sample_kernel<<<dim3(4000), blk, 0, stream>>>(kvT, offb, lgb, qb);
    // out(B,C,N) = (sampled @ Wout + bout)^T via WoutT @ sampled^T, mode 2
    gemm_swz<<<dim3(512), blk, 0, stream>>>(WoutT, qb, bout, out, nullptr,
                                            16000, 0, 0, 2, 512);
}

// Round 9
// 247.809 us; speedup vs baseline: 1.0152x; 1.0152x over previous
//
#include <hip/hip_runtime.h>
#include <math.h>

// Problem constants
#define C_DIM 512
#define NHEAD 8
#define HDIM 64
#define NTOK 8000
#define BN_TOK 16000

typedef __attribute__((ext_vector_type(8))) _Float16 f16x8;
typedef __attribute__((ext_vector_type(4))) float f32x4;
typedef __attribute__((ext_vector_type(2))) _Float16 h2;
typedef unsigned short u16;

__device__ __forceinline__ int imin(int a, int b) { return a < b ? a : b; }

// fp32 -> f16 (RNE)
__device__ __forceinline__ u16 f2h(float x) {
    _Float16 h = (_Float16)x;
    return __builtin_bit_cast(u16, h);
}

// async global->LDS, 16 bytes per lane (global_load_lds_dwordx4)
__device__ __forceinline__ void async16(const void* g, void* l) {
    __builtin_amdgcn_global_load_lds(
        (const __attribute__((address_space(1))) void*)g,
        (__attribute__((address_space(3))) void*)l, 16, 0, 0);
}

// ---------------------------------------------------------------------------
// f_kv (B,C,N) fp32 -> kvT (B,N,C) f16. Fixed 512 x 8000 per batch.
// ---------------------------------------------------------------------------
__global__ __launch_bounds__(256) void transpose_c2l_f16(
    const float* __restrict__ in, u16* __restrict__ out)
{
    __shared__ float tile[32][33];
    int b = blockIdx.z;
    const float* inb = in + (size_t)b * 512 * NTOK;
    u16* outb = out + (size_t)b * NTOK * 512;
    int s0 = blockIdx.x * 32, r0 = blockIdx.y * 32;   // s: token, r: channel
    int tx = threadIdx.x & 31, ty = threadIdx.x >> 5;
#pragma unroll
    for (int i = 0; i < 4; i++)
        tile[ty + i * 8][tx] = inb[(size_t)(r0 + ty + i * 8) * NTOK + s0 + tx];
    __syncthreads();
    int rq = threadIdx.x & 7, sy = threadIdx.x >> 3;  // rq: channel quad, sy: token
    ushort4 o;
    o.x = f2h(tile[rq * 4 + 0][sy]);
    o.y = f2h(tile[rq * 4 + 1][sy]);
    o.z = f2h(tile[rq * 4 + 2][sy]);
    o.w = f2h(tile[rq * 4 + 3][sy]);
    *reinterpret_cast<ushort4*>(outb + (size_t)(s0 + sy) * 512 + r0 + rq * 4) = o;
}

// ---------------------------------------------------------------------------
// Merged weight converts: z selects which W (512 x Nout) fp32 -> (Npad x 512)
// f16, pad rows zeroed. Grid (16,16,5); small weights early-out on x.
// ---------------------------------------------------------------------------
__global__ __launch_bounds__(256) void wcvt_all(
    const float* __restrict__ W0, u16* __restrict__ T0,
    const float* __restrict__ W1, u16* __restrict__ T1,
    const float* __restrict__ W2, u16* __restrict__ T2,
    const float* __restrict__ W3, u16* __restrict__ T3,
    const float* __restrict__ W4, u16* __restrict__ T4)
{
    const float* W; u16* Wt; int Nout, Npad;
    switch (blockIdx.z) {
        case 0: W = W0; Wt = T0; Nout = 512; Npad = 512; break;
        case 1: W = W1; Wt = T1; Nout = 512; Npad = 512; break;
        case 2: W = W2; Wt = T2; Nout = 512; Npad = 512; break;
        case 3: W = W3; Wt = T3; Nout = 96;  Npad = 128; break;
        default: W = W4; Wt = T4; Nout = 32; Npad = 128; break;
    }
    int n0 = blockIdx.x * 32, k0 = blockIdx.y * 32;
    if (n0 >= Npad) return;
    __shared__ float t[32][33];
    int tx = threadIdx.x & 31, ty = threadIdx.x >> 5;
#pragma unroll
    for (int i = 0; i < 4; i++) {
        int k = k0 + ty + i * 8, n = n0 + tx;
        t[ty + i * 8][tx] = (n < Nout) ? W[(size_t)k * Nout + n] : 0.f;
    }
    __syncthreads();
#pragma unroll
    for (int i = 0; i < 4; i++) {
        int n = n0 + ty + i * 8, k = k0 + tx;
        Wt[(size_t)n * 512 + k] = f2h(t[tx][ty + i * 8]);
    }
}

// ---------------------------------------------------------------------------
// Fused LayerNorm + (B,C,N)->(B,N,C) transpose, LDS-tiled; f16 output.
// ---------------------------------------------------------------------------
__global__ __launch_bounds__(256) void ln_fused(
    const float* __restrict__ fq, const float* __restrict__ gamma,
    const float* __restrict__ beta, u16* __restrict__ q)
{
    __shared__ float tile[512][33];   // [c][t], 67.6 KB
    __shared__ float ps[32][17], pq[32][17];
    __shared__ float muA[32], rsA[32];
    int blk = blockIdx.x;
    int b = blk / 250;
    int n0 = (blk - b * 250) * 32;
    const float* src = fq + (size_t)b * C_DIM * NTOK + n0;
    int tid = threadIdx.x;
    int cgrp = tid >> 4;          // 0..15
    int tp = (tid & 15) * 2;      // 0,2,..,30
    float s0 = 0.f, q0 = 0.f, s1 = 0.f, q1 = 0.f;
#pragma unroll 4
    for (int it = 0; it < 32; ++it) {
        int c = it * 16 + cgrp;
        float2 v = *reinterpret_cast<const float2*>(src + (size_t)c * NTOK + tp);
        tile[c][tp] = v.x; tile[c][tp + 1] = v.y;
        s0 += v.x; q0 += v.x * v.x;
        s1 += v.y; q1 += v.y * v.y;
    }
    ps[tp][cgrp] = s0; pq[tp][cgrp] = q0;
    ps[tp + 1][cgrp] = s1; pq[tp + 1][cgrp] = q1;
    int lane = tid & 63, wv = tid >> 6;
    float4 g0 = *reinterpret_cast<const float4*>(gamma + lane * 4);
    float4 be0 = *reinterpret_cast<const float4*>(beta + lane * 4);
    float4 g1 = *reinterpret_cast<const float4*>(gamma + 256 + lane * 4);
    float4 be1 = *reinterpret_cast<const float4*>(beta + 256 + lane * 4);
    __syncthreads();
    if (tid < 32) {
        float S = 0.f, SQ = 0.f;
#pragma unroll
        for (int g = 0; g < 16; ++g) { S += ps[tid][g]; SQ += pq[tid][g]; }
        float mu = S * (1.f / 512.f);
        float var = SQ * (1.f / 512.f) - mu * mu;
        muA[tid] = mu;
        rsA[tid] = rsqrtf(var + 1e-5f);
    }
    __syncthreads();
#pragma unroll
    for (int it = 0; it < 16; ++it) {
        int task = it * 4 + wv;     // 0..63 : (token, half)
        int t = task >> 1, h = task & 1;
        int c0 = h * 256 + lane * 4;
        float mu = muA[t], rs = rsA[t];
        float4 g = h ? g1 : g0, bb = h ? be1 : be0;
        ushort4 o;
        o.x = f2h((tile[c0 + 0][t] - mu) * rs * g.x + bb.x);
        o.y = f2h((tile[c0 + 1][t] - mu) * rs * g.y + bb.y);
        o.z = f2h((tile[c0 + 2][t] - mu) * rs * g.z + bb.z);
        o.w = f2h((tile[c0 + 3][t] - mu) * rs * g.w + bb.w);
        *reinterpret_cast<ushort4*>(q + ((size_t)(b * NTOK + n0 + t)) * C_DIM + c0) = o;
    }
}

// ---------------------------------------------------------------------------
// f16 MFMA GEMM body, 128Mx64N tile, BK=64 (8 K-iters), 24 KB LDS.
// Grid ~1000 blocks for the 512-col GEMMs (~4 blocks/CU): short-K GEMMs are
// prologue/latency-bound (R8: XCD swizzle neutral) — TLP hides the ramp.
// XOR swizzle over 8 segments (2-way LDS alias = free, m136).
// mode 0: fp32 row-major (ldc), bias[col]
// mode 1: f16 row-major (ldc), bias[col]
// mode 2: fp32 direct (B,C,N) store — rows=channels, cols=tokens; bias[row].
// ---------------------------------------------------------------------------
__device__ __forceinline__ void gemm_body(
    const u16* __restrict__ A, const u16* __restrict__ Bt,
    const float* __restrict__ bias, float* __restrict__ Cf,
    u16* __restrict__ Ch, int Nout, int ldc, int relu, int mode,
    int bx, int by)
{
    __shared__ u16 As[128 * 64];  // 16 KB
    __shared__ u16 Bs[64 * 64];   // 8 KB
    int tid = threadIdx.x, lane = tid & 63, wv = tid >> 6;
    int bm = by * 128, bn = bx * 64;
    int wm = (wv >> 1) * 64, wn = (wv & 1) * 32;

    f32x4 acc[4][2];
#pragma unroll
    for (int i = 0; i < 4; i++)
#pragma unroll
        for (int j = 0; j < 2; j++) acc[i][j] = (f32x4){0.f, 0.f, 0.f, 0.f};

    // A: 1024 16B chunks (4/thread); B: 512 chunks (2/thread)
    int rA[4], sA[4], dA[4];
#pragma unroll
    for (int c = 0; c < 4; c++) {
        int lin = (c * 4 + wv) * 64 + lane;
        rA[c] = lin >> 3;
        sA[c] = (lin & 7) ^ (rA[c] & 7);
        dA[c] = lin * 8;   // u16 units
    }

    const u16* Ab = A + (size_t)bm * 512;
    const u16* Bb = Bt + (size_t)bn * 512;

    int ml = lane & 15, quad = lane >> 4;
    int offA[4][2], offB[2][2];
#pragma unroll
    for (int i = 0; i < 4; i++) {
        int r = wm + i * 16 + ml;
#pragma unroll
        for (int kk = 0; kk < 2; kk++)
            offA[i][kk] = r * 64 + (((kk * 4 + quad) ^ (r & 7)) * 8);
    }
#pragma unroll
    for (int j = 0; j < 2; j++) {
        int rb = wn + j * 16 + ml;
#pragma unroll
        for (int kk = 0; kk < 2; kk++)
            offB[j][kk] = rb * 64 + (((kk * 4 + quad) ^ (rb & 7)) * 8);
    }

    for (int k0 = 0; k0 < 512; k0 += 64) {
#pragma unroll
        for (int c = 0; c < 4; c++)
            async16(Ab + (size_t)rA[c] * 512 + k0 + sA[c] * 8, As + dA[c]);
#pragma unroll
        for (int c = 0; c < 2; c++)
            async16(Bb + (size_t)rA[c] * 512 + k0 + sA[c] * 8, Bs + dA[c]);
        __syncthreads();
#pragma unroll
        for (int kk = 0; kk < 2; kk++) {
            f16x8 af[4], bf[2];
#pragma unroll
            for (int i = 0; i < 4; i++)
                af[i] = *reinterpret_cast<const f16x8*>(As + offA[i][kk]);
#pragma unroll
            for (int j = 0; j < 2; j++)
                bf[j] = *reinterpret_cast<const f16x8*>(Bs + offB[j][kk]);
#pragma unroll
            for (int i = 0; i < 4; i++)
#pragma unroll
                for (int j = 0; j < 2; j++)
                    acc[i][j] = __builtin_amdgcn_mfma_f32_16x16x32_f16(
                        af[i], bf[j], acc[i][j], 0, 0, 0);
        }
        __syncthreads();
    }

    // epilogue: C/D layout col=lane&15, row=quad*4+reg (m89/m91 verified)
#pragma unroll
    for (int i = 0; i < 4; i++) {
        int row = bm + wm + i * 16 + quad * 4;
#pragma unroll
        for (int j = 0; j < 2; j++) {
            int col = bn + wn + j * 16 + ml;
            if (col < Nout) {
                float bia = (mode == 2) ? 0.f : bias[col];
#pragma unroll
                for (int rg = 0; rg < 4; rg++) {
                    float v = acc[i][j][rg] + ((mode == 2) ? bias[row + rg] : bia);
                    if (relu) v = fmaxf(v, 0.f);
                    if (mode == 2) {
                        int bb = col >= 8000;
                        int nn = col - bb * 8000;
                        Cf[((size_t)(bb * 512 + row + rg)) * 8000 + nn] = v;
                    } else {
                        size_t idx = (size_t)(row + rg) * ldc + col;
                        if (mode == 1) Ch[idx] = f2h(v);
                        else           Cf[idx] = v;
                    }
                }
            }
        }
    }
}

__global__ __launch_bounds__(256) void gemm_f16(
    const u16* __restrict__ A, const u16* __restrict__ Bt,
    const float* __restrict__ bias, float* __restrict__ Cf,
    u16* __restrict__ Ch, int Nout, int ldc, int relu, int mode)
{
    gemm_body(A, Bt, bias, Cf, Ch, Nout, ldc, relu, mode,
              blockIdx.x, blockIdx.y);
}

// Two independent small GEMMs in one dispatch (z selects operand set).
// z=0: off (Nout=96, 2 col-tiles); z=1: logits (Nout=32, 1 col-tile).
__global__ __launch_bounds__(256) void gemm_dual(
    const u16* __restrict__ A0, const u16* __restrict__ B0,
    const float* __restrict__ bias0, float* __restrict__ C0, int N0,
    const u16* __restrict__ A1, const u16* __restrict__ B1,
    const float* __restrict__ bias1, float* __restrict__ C1, int N1)
{
    if (blockIdx.z == 0)
        gemm_body(A0, B0, bias0, C0, nullptr, N0, N0, 0, 0,
                  blockIdx.x, blockIdx.y);
    else {
        if (blockIdx.x > 0) return;   // logits fits one 64-col tile
        gemm_body(A1, B1, bias1, C1, nullptr, N1, N1, 0, 0,
                  blockIdx.x, blockIdx.y);
    }
}

// ---------------------------------------------------------------------------
// Fused softmax + offset clip + trilinear sample + einsum, f16 volume.
// One wave = one token (8 heads); lane = h*8 + cl, 8 channels/lane via one
// uint4 (8 x f16) corner load. Channels accumulate as 4 x h2 via
// v_pk_fma_f16 (2 ch/inst, halves the R7 inner fma count); result stored
// raw as f16 (consumed by the f16 out-GEMM). p-loop NOT unrolled (R6: full
// unroll -> 132 VGPR -> 9% occ). 32-bit element offsets.
// XCD swizzle: blockIdx.x & 7 -> 2000-token contiguous slab per XCD.
// Reference quirk: off-ch0 -> W(x) axis, ch1 -> H(y), ch2 -> D(z); H=W=D=20
// collapses normalization to clip(base+off, 0, 19).
// ---------------------------------------------------------------------------
__global__ __launch_bounds__(256) void sample_kernel(
    const u16* __restrict__ vol, const float* __restrict__ offb,
    const float* __restrict__ lgb, u16* __restrict__ outp)
{
    int wid = threadIdx.x >> 6, lane = threadIdx.x & 63;
    int bx = blockIdx.x;                               // 4000 = 8 slabs x 500
    int bn = ((bx & 7) * 500 + (bx >> 3)) * 4 + wid;   // token 0..15999
    int h = lane >> 3, cl = lane & 7;
    int b = bn / NTOK, n = bn - b * NTOK;
    int y = n / 400;
    int r2 = n - y * 400;
    int x = r2 / 20;
    int z = r2 - x * 20;

    const float* op = offb + (size_t)bn * 96 + h * 12;
    const float* lp = lgb + (size_t)bn * 32 + h * 4;
    float l0 = lp[0], l1 = lp[1], l2 = lp[2], l3 = lp[3];
    float mx = fmaxf(fmaxf(l0, l1), fmaxf(l2, l3));
    float e0 = expf(l0 - mx), e1 = expf(l1 - mx), e2 = expf(l2 - mx), e3 = expf(l3 - mx);
    float inv = 1.f / (e0 + e1 + e2 + e3);
    float at[4] = {e0 * inv, e1 * inv, e2 * inv, e3 * inv};

    const u16* volb = vol + b * (NTOK * C_DIM) + h * HDIM + cl * 8;
    h2 acc0 = (h2)(_Float16)0, acc1 = acc0, acc2 = acc0, acc3 = acc0;
#pragma unroll 1
    for (int p = 0; p < 4; p++) {
        float o0 = fminf(fmaxf(op[p * 3 + 0], -3.f), 3.f);
        float o1 = fminf(fmaxf(op[p * 3 + 1], -3.f), 3.f);
        float o2 = fminf(fmaxf(op[p * 3 + 2], -3.f), 3.f);
        float ix = fminf(fmaxf((float)y + o0, 0.f), 19.f);  // W axis
        float iy = fminf(fmaxf((float)x + o1, 0.f), 19.f);  // H axis
        float iz = fminf(fmaxf((float)z + o2, 0.f), 19.f);  // D axis
        float xf = floorf(ix), yf = floorf(iy), zf = floorf(iz);
        float fx = ix - xf, fy = iy - yf, fz = iz - zf;
        int x0 = (int)xf, y0 = (int)yf, z0 = (int)zf;
        int x1 = imin(x0 + 1, 19), y1 = imin(y0 + 1, 19), z1 = imin(z0 + 1, 19);
        // spatial = yi*400 + xi*20 + zi, channels contiguous (stride C_DIM)
        int s00 = y0 * 400 + x0 * 20, s01 = y0 * 400 + x1 * 20;
        int s10 = y1 * 400 + x0 * 20, s11 = y1 * 400 + x1 * 20;
        uint4 v000 = *(const uint4*)(volb + (s00 + z0) * C_DIM);
        uint4 v001 = *(const uint4*)(volb + (s01 + z0) * C_DIM);
        uint4 v010 = *(const uint4*)(volb + (s10 + z0) * C_DIM);
        uint4 v011 = *(const uint4*)(volb + (s11 + z0) * C_DIM);
        uint4 v100 = *(const uint4*)(volb + (s00 + z1) * C_DIM);
        uint4 v101 = *(const uint4*)(volb + (s01 + z1) * C_DIM);
        uint4 v110 = *(const uint4*)(volb + (s10 + z1) * C_DIM);
        uint4 v111 = *(const uint4*)(volb + (s11 + z1) * C_DIM);
        float wz0 = (1.f - fz) * at[p], wz1 = fz * at[p];
        float w00 = wz0 * (1.f - fy), w01 = wz0 * fy;
        float w10 = wz1 * (1.f - fy), w11 = wz1 * fy;
        float gx0 = 1.f - fx;
        float cw[8] = { w00 * gx0, w00 * fx, w01 * gx0, w01 * fx,
                        w10 * gx0, w10 * fx, w11 * gx0, w11 * fx };
        const uint4* cv[8] = { &v000, &v001, &v010, &v011,
                               &v100, &v101, &v110, &v111 };
#pragma unroll
        for (int c = 0; c < 8; c++) {
            _Float16 wh = (_Float16)cw[c];
            h2 w2; w2.x = wh; w2.y = wh;
            uint4 d = *cv[c];
            acc0 += __builtin_bit_cast(h2, d.x) * w2;
            acc1 += __builtin_bit_cast(h2, d.y) * w2;
            acc2 += __builtin_bit_cast(h2, d.z) * w2;
            acc3 += __builtin_bit_cast(h2, d.w) * w2;
        }
    }
    uint4 o;
    o.x = __builtin_bit_cast(unsigned, acc0);
    o.y = __builtin_bit_cast(unsigned, acc1);
    o.z = __builtin_bit_cast(unsigned, acc2);
    o.w = __builtin_bit_cast(unsigned, acc3);
    *reinterpret_cast<uint4*>(outp + (size_t)bn * C_DIM + h * HDIM + cl * 8) = o;
}

// ---------------------------------------------------------------------------
// Launch
// ---------------------------------------------------------------------------
extern "C" void kernel_launch(void* const* d_in, const int* in_sizes, int n_in,
                              void* d_out, int out_size, void* d_ws, size_t ws_size,
                              hipStream_t stream)
{
    const float* f_query = (const float*)d_in[0];
    const float* f_kv    = (const float*)d_in[1];
    const float* ln_g    = (const float*)d_in[2];
    const float* ln_b    = (const float*)d_in[3];
    const float* Wq      = (const float*)d_in[4];
    const float* bq      = (const float*)d_in[5];
    const float* Wo1     = (const float*)d_in[6];
    const float* bo1     = (const float*)d_in[7];
    const float* Wo2     = (const float*)d_in[8];
    const float* bo2     = (const float*)d_in[9];
    const float* Wa      = (const float*)d_in[10];
    const float* ba      = (const float*)d_in[11];
    const float* Wout    = (const float*)d_in[12];
    const float* bout    = (const float*)d_in[13];
    float* out = (float*)d_out;

    float* ws = (float*)d_ws;
    float* offb = ws;                     // 1,536,000 f
    float* lgb  = ws + 1536000;           //   512,000 f
    u16* kvT   = (u16*)(ws + 2048000);    // 16000x512 (f16 channels-last)
    u16* qb    = kvT  + 8192000;          // 16000x512 (q; later sampled)
    u16* Qb    = qb   + 8192000;          // 16000x512
    u16* hid   = Qb   + 8192000;          // 16000x512
    u16* WqT   = hid  + 8192000;          // 512x512
    u16* Wo1T  = WqT + 262144;
    u16* WoutT = Wo1T + 262144;
    u16* Wo2T  = WoutT + 262144;          // 128x512 (96 valid, pad 0)
    u16* WaT   = Wo2T + 65536;            // 128x512 (32 valid, pad 0)
    // total ~75.6 MiB

    dim3 blk(256);
    // all weight transpose-converts in one dispatch (fp32 -> f16 N^T x K)
    wcvt_all<<<dim3(16, 16, 5), blk, 0, stream>>>(
        Wq, WqT, Wo1, Wo1T, Wout, WoutT, Wo2, Wo2T, Wa, WaT);
    // f_kv (B,C,N) fp32 -> kvT (B,N,C) f16
    transpose_c2l_f16<<<dim3(250, 16, 2), blk, 0, stream>>>(f_kv, kvT);
    // q = LN(transpose(f_query)) -> f16, fused LDS tile
    ln_fused<<<dim3(500), blk, 0, stream>>>(f_query, ln_g, ln_b, qb);
    // Q = q @ Wq + bq -> f16
    gemm_f16<<<dim3(8, 125), blk, 0, stream>>>(qb, WqT, bq, nullptr, Qb,
                                               512, 512, 0, 1);
    // hidden = relu(Q @ Wo1 + bo1) -> f16
    gemm_f16<<<dim3(8, 125), blk, 0, stream>>>(Qb, Wo1T, bo1, nullptr, hid,
                                               512, 512, 1, 1);
    // off = hidden @ Wo2 + bo2 (fp32) AND logits = Q @ Wa + ba (fp32)
    gemm_dual<<<dim3(2, 125, 2), blk, 0, stream>>>(
        hid, Wo2T, bo2, offb, 96, Qb, WaT, ba, lgb, 32);
    // fused sample/softmax/einsum -> qb (f16, raw h2 store)
    sample_kernel<<<dim3(4000), blk, 0, stream>>>(kvT, offb, lgb, qb);
    // out(B,C,N) = (sampled @ Wout + bout)^T via WoutT @ sampled^T, mode 2
    gemm_f16<<<dim3(250, 4), blk, 0, stream>>>(WoutT, qb, bout, out, nullptr,
                                               16000, 0, 0, 2);
}